// Round 7
// baseline (495.020 us; speedup 1.0000x reference)
//
#include <hip/hip_runtime.h>

// ---------------------------------------------------------------------------
// KAN net. gr = n*16 + w; xa[gr,i] = x[n*8464 + i*16 + w].
// k_l1: layer1 (32768,529)->(32768,40) via 32x32x16 bf16 MFMA, 3-term
//       hi/lo split precision. Wave = 32 rows; K-step = one i (q=8*(l>>5)+j).
//       3-way i-split -> h1p[3] f32 partials. No LDS.
// k_l2: sum partials, layer2 (40->60) f32 VALU -> h2d[n][o*16+w]
// k_lin1head: lin1(960->512)+l2norm+spline act+lin2+l2norm -> f32 out.
// ws 25.6 MB: bhi/blo aliased inside h2d region (dead before k_l2 writes it).
// ---------------------------------------------------------------------------

typedef short bf16x8 __attribute__((ext_vector_type(8)));
typedef float f32x16 __attribute__((ext_vector_type(16)));

__device__ __forceinline__ float siluf(float x) { return x / (1.f + __expf(-x)); }

__device__ __forceinline__ unsigned short f2bf_rne(float v) {
    union { float f; unsigned u; } a; a.f = v;
    return (unsigned short)((a.u + 0x7fffu + ((a.u >> 16) & 1u)) >> 16);
}
__device__ __forceinline__ float bf2f(unsigned short h) {
    union { unsigned u; float f; } a; a.u = ((unsigned)h) << 16;
    return a.f;
}

// Dense 8-wide cubic B-spline, uniform grid t_j=(j-3)*0.4-1 (validated vs
// literal Cox-de Boor in the r2 bisection build).
__device__ __forceinline__ void bspline8(float x, float fm[8]) {
    float tpos = (x + 2.2f) * 2.5f;
    float fc = floorf(tpos);
    int c = (int)fc;
    float u = tpos - fc;
    bool valid = (c >= 0) && (c <= 10);
    float om = 1.f - u;
    float u2 = u * u, u3 = u2 * u;
    float W0 = om * om * om * (1.f / 6.f);
    float W1 = (3.f * u3 - 6.f * u2 + 4.f) * (1.f / 6.f);
    float W2 = (-3.f * u3 + 3.f * u2 + 3.f * u + 1.f) * (1.f / 6.f);
    float W3 = u3 * (1.f / 6.f);
#pragma unroll
    for (int m = 0; m < 8; ++m) {
        int d = c - m;
        float v = (d == 3) ? W0 : 0.f;
        v = (d == 2) ? W1 : v;
        v = (d == 1) ? W2 : v;
        v = (d == 0) ? W3 : v;
        fm[m] = valid ? v : 0.f;
    }
}

// ---------------------------------------------------------------------------
// k_prep:
//  bhi/blo[((i*2+nt)*64+l)*8+j] = bf16 hi/lo of B[k][o], k-slot q=(l>>5)*8+j,
//     o = nt*32+(l&31); q0=base_w1, q1..8=spline_w1, else/o>=40 -> 0.
//  w2t[i][q][60]; wq[dq][u][4] = lin1_w[u][dq*4+r]
// ---------------------------------------------------------------------------
__global__ __launch_bounds__(256) void k_prep(
    const float* __restrict__ base_w1, const float* __restrict__ spline_w1,
    const float* __restrict__ base_w2, const float* __restrict__ spline_w2,
    const float* __restrict__ lin1_w,
    unsigned short* __restrict__ bhi, unsigned short* __restrict__ blo,
    float* __restrict__ w2t, float* __restrict__ wq) {
    int gid = blockIdx.x * 256 + threadIdx.x;
    int stride = gridDim.x * 256;
    for (int idx = gid; idx < 529 * 2 * 512; idx += stride) {
        int j = idx & 7;
        int l = (idx >> 3) & 63;
        int nti = idx >> 9;
        int nt = nti & 1;
        int i = nti >> 1;
        int q = ((l >> 5) << 3) + j;
        int o = nt * 32 + (l & 31);
        float val = 0.f;
        if (o < 40 && q <= 8)
            val = (q == 0) ? base_w1[o * 529 + i]
                           : spline_w1[(o * 529 + i) * 8 + (q - 1)];
        unsigned short h = f2bf_rne(val);
        bhi[idx] = h;
        blo[idx] = f2bf_rne(val - bf2f(h));
    }
    for (int idx = gid; idx < 40 * 540; idx += stride) {
        int i = idx / 540;
        int rem = idx - i * 540;
        int q = rem / 60;
        int o = rem - q * 60;
        w2t[idx] = (q == 0) ? base_w2[o * 40 + i]
                            : spline_w2[(o * 40 + i) * 8 + (q - 1)];
    }
    for (int idx = gid; idx < 240 * 512 * 4; idx += stride) {
        int dq = idx >> 11;
        int rem = idx & 2047;
        int u = rem >> 2;
        int r = rem & 3;
        wq[idx] = lin1_w[u * 960 + dq * 4 + r];
    }
}

// ---------------------------------------------------------------------------
// k_l1: 768 blocks (256 row-blocks x 3 i-splits) x 256 thr (4 waves).
// Wave = 32 rows gr0..gr0+31. Lane: A-row/B-col = l&31, k-octet g2 = l>>5.
// Per i: features f32 -> av[8] (g2=0: silu,fm0..6; g2=1: fm7,0..0) ->
// truncate-split hi/lo -> 6 MFMAs (2 n-tiles x {ah*bh, ah*bl, al*bh}).
// ---------------------------------------------------------------------------
__global__ __launch_bounds__(256) void k_l1(
    const float* __restrict__ x, const unsigned short* __restrict__ bhi,
    const unsigned short* __restrict__ blo, float* __restrict__ h1p) {
    int t = threadIdx.x;
    int l = t & 63;
    int wv = t >> 6;
    int rb = blockIdx.x & 255;
    int split = blockIdx.x >> 8;         // 0..2
    int gr0 = rb * 128 + wv * 32;
    int col = l & 31;                    // A-row on load side, o-col on store
    int g2 = l >> 5;
    int gr = gr0 + col;
    const float* xrow = x + (size_t)(gr >> 4) * 8464 + (gr & 15);

    f32x16 acc0, acc1;
#pragma unroll
    for (int r = 0; r < 16; ++r) { acc0[r] = 0.f; acc1[r] = 0.f; }

    int i_lo = split * 177;
    int i_hi = i_lo + 177 < 529 ? i_lo + 177 : 529;

    float xv_nxt = xrow[(size_t)i_lo * 16];
#pragma unroll 1
    for (int i = i_lo; i < i_hi; ++i) {
        float xv = xv_nxt;
        int inx = i + 1;
        xv_nxt = (inx < i_hi) ? xrow[(size_t)inx * 16] : 0.f;

        float s0 = siluf(xv);
        float fm[8];
        bspline8(xv, fm);

        float av[8];
        av[0] = g2 ? fm[7] : s0;
#pragma unroll
        for (int j = 1; j < 8; ++j) av[j] = g2 ? 0.f : fm[j - 1];

        bf16x8 ahi, alo;
#pragma unroll
        for (int j = 0; j < 8; ++j) {
            union { float f; unsigned u; } a; a.f = av[j];
            unsigned short h = (unsigned short)(a.u >> 16);   // truncate hi
            ahi[j] = (short)h;
            union { float f; unsigned u; } r; r.f = av[j] - bf2f(h);
            alo[j] = (short)(r.u >> 16);                      // truncate lo
        }

        const bf16x8* bh = (const bf16x8*)(bhi + ((size_t)i * 2) * 512 + (size_t)l * 8);
        const bf16x8* bl = (const bf16x8*)(blo + ((size_t)i * 2) * 512 + (size_t)l * 8);
        bf16x8 bh0 = bh[0], bh1 = bh[64];
        bf16x8 bl0 = bl[0], bl1 = bl[64];

        acc0 = __builtin_amdgcn_mfma_f32_32x32x16_bf16(ahi, bh0, acc0, 0, 0, 0);
        acc1 = __builtin_amdgcn_mfma_f32_32x32x16_bf16(ahi, bh1, acc1, 0, 0, 0);
        acc0 = __builtin_amdgcn_mfma_f32_32x32x16_bf16(ahi, bl0, acc0, 0, 0, 0);
        acc1 = __builtin_amdgcn_mfma_f32_32x32x16_bf16(ahi, bl1, acc1, 0, 0, 0);
        acc0 = __builtin_amdgcn_mfma_f32_32x32x16_bf16(alo, bh0, acc0, 0, 0, 0);
        acc1 = __builtin_amdgcn_mfma_f32_32x32x16_bf16(alo, bh1, acc1, 0, 0, 0);
    }

    // D: col = l&31, row = (reg&3) + 8*(reg>>2) + 4*g2
    float* hp = h1p + (size_t)split * 1310720;
#pragma unroll
    for (int reg = 0; reg < 16; ++reg) {
        int rl = (reg & 3) + 8 * (reg >> 2) + 4 * g2;
        size_t g = (size_t)(gr0 + rl);
        hp[g * 40 + col] = acc0[reg];
        if (col < 8) hp[g * 40 + 32 + col] = acc1[reg];
    }
}

// ---------------------------------------------------------------------------
// k_l2: 512 blocks (128 rowchunks x 4 o-quarters) x 256 thr. Stage+sum the
// three i-split partials in LDS (stride 41), thread = one row, 15 outputs.
// ---------------------------------------------------------------------------
__global__ __launch_bounds__(256) void k_l2(
    const float* __restrict__ h1p, const float* __restrict__ w2t,
    float* __restrict__ h2d) {
    __shared__ float lds[256 * 41];
    int t = threadIdx.x;
    int rc = blockIdx.x >> 2;
    int oq = blockIdx.x & 3;
    size_t base = (size_t)rc * 10240;

#pragma unroll 1
    for (int e = t; e < 10240; e += 256) {
        int r = e / 40;
        int i = e - r * 40;
        lds[r * 41 + i] = h1p[base + e] + h1p[1310720 + base + e] +
                          h1p[2621440 + base + e];
    }
    __syncthreads();

    float acc[15];
#pragma unroll
    for (int oo = 0; oo < 15; ++oo) acc[oo] = 0.f;

#pragma unroll 1
    for (int i = 0; i < 40; ++i) {
        float hv = lds[t * 41 + i];
        float f[9];
        f[0] = siluf(hv);
        bspline8(hv, f + 1);
        const float* wp = w2t + i * 540 + oq * 15;   // uniform -> s_load
#pragma unroll
        for (int q = 0; q < 9; ++q) {
            float fv = f[q];
#pragma unroll
            for (int oo = 0; oo < 15; ++oo)
                acc[oo] = fmaf(fv, wp[q * 60 + oo], acc[oo]);
        }
    }
    int gr = rc * 256 + t;
    int n = gr >> 4, w = gr & 15;
    float* op = h2d + (size_t)n * 960 + w;
#pragma unroll
    for (int oo = 0; oo < 15; ++oo)
        op[(size_t)(oq * 15 + oo) * 16] = acc[oo];
}

// ---------------------------------------------------------------------------
// k_lin1head: 256 blocks x 512 thr, block = 8 rows.
// ---------------------------------------------------------------------------
__global__ __launch_bounds__(512) void k_lin1head(
    const float* __restrict__ h2d, const float* __restrict__ wq,
    const float* __restrict__ lin1_b, const float* __restrict__ act_base,
    const float* __restrict__ act_coeff, const float* __restrict__ lin2_w,
    const float* __restrict__ lin2_b, float* __restrict__ out) {
    __shared__ float smem[8 * 960];
    int t = threadIdx.x;
    int n0 = blockIdx.x * 8;

#pragma unroll 1
    for (int e = t; e < 7680; e += 512)
        smem[e] = h2d[(size_t)n0 * 960 + e];
    __syncthreads();

    float acc[8];
#pragma unroll
    for (int nn = 0; nn < 8; ++nn) acc[nn] = 0.f;

    const float4* wq4 = (const float4*)wq;
#pragma unroll 1
    for (int dq = 0; dq < 240; ++dq) {
        float4 wv = wq4[(size_t)dq * 512 + t];
#pragma unroll
        for (int nn = 0; nn < 8; ++nn) {
            float4 rv = *(const float4*)&smem[nn * 960 + dq * 4];
            float a = acc[nn];
            a = fmaf(rv.x, wv.x, a);
            a = fmaf(rv.y, wv.y, a);
            a = fmaf(rv.z, wv.z, a);
            a = fmaf(rv.w, wv.w, a);
            acc[nn] = a;
        }
    }
    float bu = lin1_b[t];
    __syncthreads();
#pragma unroll
    for (int nn = 0; nn < 8; ++nn)
        smem[nn * 512 + t] = acc[nn] + bu;
    __syncthreads();

    int wv = t >> 6, lane = t & 63;
    int n = n0 + wv;
    const float* hr = smem + wv * 512;

    float xv[8];
#pragma unroll
    for (int k = 0; k < 8; ++k) xv[k] = hr[lane + 64 * k];
    float ss = 0.f;
#pragma unroll
    for (int k = 0; k < 8; ++k) ss = fmaf(xv[k], xv[k], ss);
#pragma unroll
    for (int d = 1; d < 64; d <<= 1) ss += __shfl_xor(ss, d, 64);
    float scale = 1.f / fmaxf(sqrtf(ss), 1e-12f);

    float act[8];
#pragma unroll
    for (int k = 0; k < 8; ++k) {
        int u = lane + 64 * k;
        float hn = xv[k] * scale;
        float s = siluf(hn);
        float fm[8];
        bspline8(hn, fm);
        float4 c0 = *(const float4*)(act_coeff + (size_t)u * 8);
        float4 c1 = *(const float4*)(act_coeff + (size_t)u * 8 + 4);
        float a = act_base[u] * s;
        a = fmaf(fm[0], c0.x, a);
        a = fmaf(fm[1], c0.y, a);
        a = fmaf(fm[2], c0.z, a);
        a = fmaf(fm[3], c0.w, a);
        a = fmaf(fm[4], c1.x, a);
        a = fmaf(fm[5], c1.y, a);
        a = fmaf(fm[6], c1.z, a);
        a = fmaf(fm[7], c1.w, a);
        act[k] = a;
    }

    float y = 0.f;
#pragma unroll
    for (int v = 0; v < 16; ++v) {
        float pv = 0.f;
#pragma unroll
        for (int k = 0; k < 8; ++k)
            pv = fmaf(act[k], lin2_w[v * 512 + lane + 64 * k], pv);
#pragma unroll
        for (int d = 1; d < 64; d <<= 1) pv += __shfl_xor(pv, d, 64);
        if (lane == v) y = pv + lin2_b[v];
    }
    float qq = y * y;
#pragma unroll
    for (int d = 1; d < 16; d <<= 1) qq += __shfl_xor(qq, d, 64);
    float sc2 = 1.f / fmaxf(sqrtf(qq), 1e-12f);
    if (lane < 16)
        out[(size_t)n * 16 + lane] = y * sc2;
}

// ---------------------------------------------------------------------------
extern "C" void kernel_launch(void* const* d_in, const int* in_sizes, int n_in,
                              void* d_out, int out_size, void* d_ws,
                              size_t ws_size, hipStream_t stream) {
    auto find = [&](int sz, int occur) -> const float* {
        int seen = 0;
        for (int i = 0; i < n_in; ++i) {
            if (in_sizes[i] == sz) {
                if (seen == occur) return (const float*)d_in[i];
                ++seen;
            }
        }
        return nullptr;
    };
    const float* x         = find(17334272, 0);
    const float* base_w1   = find(21160, 0);
    const float* spline_w1 = find(169280, 0);
    const float* base_w2   = find(2400, 0);
    const float* spline_w2 = find(19200, 0);
    const float* lin1_w    = find(491520, 0);
    const float* lin1_b    = find(512, 0);
    const float* act_base  = find(512, 1);
    const float* act_coeff = find(4096, 0);
    const float* lin2_w    = find(8192, 0);
    const float* lin2_b    = find(16, 0);
    if (!x || !base_w1 || !spline_w1 || !base_w2 || !spline_w2 || !lin1_w ||
        !lin1_b || !act_base || !act_coeff || !lin2_w || !lin2_b) {
        x         = (const float*)d_in[0];
        base_w1   = (const float*)d_in[3];
        spline_w1 = (const float*)d_in[4];
        base_w2   = (const float*)d_in[6];
        spline_w2 = (const float*)d_in[7];
        lin1_w    = (const float*)d_in[8];
        lin1_b    = (const float*)d_in[9];
        act_base  = (const float*)d_in[11];
        act_coeff = (const float*)d_in[12];
        lin2_w    = (const float*)d_in[13];
        lin2_b    = (const float*)d_in[14];
    }

    char* ws = (char*)d_ws;
    float* w2t = (float*)ws;                          // 86400 B
    float* wq  = (float*)(ws + 86400);                // 1966080 B
    float* h2d = (float*)(ws + 2052480);              // 7864320 B
    // bhi/blo alias the h2d region: written by k_prep, read by k_l1, then
    // fully overwritten by k_l2's h2d stores (strictly later in-stream).
    unsigned short* bhi = (unsigned short*)(ws + 2052480);
    unsigned short* blo = bhi + 541696;               // 2 x 1083392 B <= h2d
    float* h1p = (float*)(ws + 9916800);              // 3 x 5242880 B
    // total 25,645,440 B (30.7 MB proven usable in r0)

    k_prep<<<1024, 256, 0, stream>>>(base_w1, spline_w1, base_w2, spline_w2,
                                     lin1_w, bhi, blo, w2t, wq);
    k_l1<<<768, 256, 0, stream>>>(x, bhi, blo, h1p);
    k_l2<<<512, 256, 0, stream>>>(h1p, w2t, h2d);
    k_lin1head<<<256, 512, 0, stream>>>(h2d, wq, lin1_b, act_base, act_coeff,
                                        lin2_w, lin2_b, (float*)d_out);
}

// Round 8
// 379.874 us; speedup vs baseline: 1.3031x; 1.3031x over previous
//
#include <hip/hip_runtime.h>

// ---------------------------------------------------------------------------
// KAN net. gr = n*16 + w; xa[gr,i] = x[n*8464 + i*16 + w].
// k_l1: layer1 (32768,529)->(32768,40), 32x32x16 bf16 MFMA, 3-term hi/lo
//       split. 6-way i-split -> h1p[6] f16 partials. 1536 blocks (6/CU).
// k_l2: sum 6 f16 partials, layer2 (40->60) f32 VALU -> h2d[n][o*16+w]
// k3:   lin1 (2048x960)x(960x512) via same MFMA convention, W pre-split.
// k4:   l2norm + spline act + lin2 + l2norm -> f32 out.
// ws 29.84 MB (r0 proved >= 30.67 usable). bhi/blo alias h2d region.
// ---------------------------------------------------------------------------

typedef short bf16x8 __attribute__((ext_vector_type(8)));
typedef float f32x16 __attribute__((ext_vector_type(16)));

__device__ __forceinline__ float siluf(float x) { return x / (1.f + __expf(-x)); }

__device__ __forceinline__ unsigned short f2bf_rne(float v) {
    union { float f; unsigned u; } a; a.f = v;
    return (unsigned short)((a.u + 0x7fffu + ((a.u >> 16) & 1u)) >> 16);
}
__device__ __forceinline__ float bf2f(unsigned short h) {
    union { unsigned u; float f; } a; a.u = ((unsigned)h) << 16;
    return a.f;
}

// Dense 8-wide cubic B-spline, uniform grid t_j=(j-3)*0.4-1 (validated vs
// literal Cox-de Boor in the r2 bisection build).
__device__ __forceinline__ void bspline8(float x, float fm[8]) {
    float tpos = (x + 2.2f) * 2.5f;
    float fc = floorf(tpos);
    int c = (int)fc;
    float u = tpos - fc;
    bool valid = (c >= 0) && (c <= 10);
    float om = 1.f - u;
    float u2 = u * u, u3 = u2 * u;
    float W0 = om * om * om * (1.f / 6.f);
    float W1 = (3.f * u3 - 6.f * u2 + 4.f) * (1.f / 6.f);
    float W2 = (-3.f * u3 + 3.f * u2 + 3.f * u + 1.f) * (1.f / 6.f);
    float W3 = u3 * (1.f / 6.f);
#pragma unroll
    for (int m = 0; m < 8; ++m) {
        int d = c - m;
        float v = (d == 3) ? W0 : 0.f;
        v = (d == 2) ? W1 : v;
        v = (d == 1) ? W2 : v;
        v = (d == 0) ? W3 : v;
        fm[m] = valid ? v : 0.f;
    }
}

// ---------------------------------------------------------------------------
// k_prep:
//  bhi/blo[((i*2+nt)*64+l)*8+j]: bf16 hi/lo of B1[k][o], q=(l>>5)*8+j,
//     o=nt*32+(l&31); q0=base_w1, q1..8=spline_w1, else 0.  (k_l1 B)
//  whi/wlo[((dq*16+ct)*64+l)*8+j]: lin1_w[u=ct*32+(l&31)][k=dq*16+(l>>5)*8+j]
//  w2t[i][q][60]
// ---------------------------------------------------------------------------
__global__ __launch_bounds__(256) void k_prep(
    const float* __restrict__ base_w1, const float* __restrict__ spline_w1,
    const float* __restrict__ base_w2, const float* __restrict__ spline_w2,
    const float* __restrict__ lin1_w,
    unsigned short* __restrict__ bhi, unsigned short* __restrict__ blo,
    unsigned short* __restrict__ whi, unsigned short* __restrict__ wlo,
    float* __restrict__ w2t) {
    int gid = blockIdx.x * 256 + threadIdx.x;
    int stride = gridDim.x * 256;
    for (int idx = gid; idx < 529 * 2 * 512; idx += stride) {
        int j = idx & 7;
        int l = (idx >> 3) & 63;
        int nti = idx >> 9;
        int nt = nti & 1;
        int i = nti >> 1;
        int q = ((l >> 5) << 3) + j;
        int o = nt * 32 + (l & 31);
        float val = 0.f;
        if (o < 40 && q <= 8)
            val = (q == 0) ? base_w1[o * 529 + i]
                           : spline_w1[(o * 529 + i) * 8 + (q - 1)];
        unsigned short h = f2bf_rne(val);
        bhi[idx] = h;
        blo[idx] = f2bf_rne(val - bf2f(h));
    }
    for (int idx = gid; idx < 60 * 16 * 512; idx += stride) {
        int j = idx & 7;
        int l = (idx >> 3) & 63;
        int ctdq = idx >> 9;
        int ct = ctdq & 15;
        int dq = ctdq >> 4;
        int k = dq * 16 + ((l >> 5) << 3) + j;
        int u = ct * 32 + (l & 31);
        float val = lin1_w[(size_t)u * 960 + k];
        unsigned short h = f2bf_rne(val);
        whi[idx] = h;
        wlo[idx] = f2bf_rne(val - bf2f(h));
    }
    for (int idx = gid; idx < 40 * 540; idx += stride) {
        int i = idx / 540;
        int rem = idx - i * 540;
        int q = rem / 60;
        int o = rem - q * 60;
        w2t[idx] = (q == 0) ? base_w2[o * 40 + i]
                            : spline_w2[(o * 40 + i) * 8 + (q - 1)];
    }
}

// ---------------------------------------------------------------------------
// k_l1: 1536 blocks (256 row-blocks x 6 i-splits) x 256 thr (4 waves).
// Wave = 32 rows. Lane: A-row/B-col = l&31, k-octet g2 = l>>5.
// 6 MFMAs per i (2 n-tiles x {ah*bh, ah*bl, al*bh}). f16 partial stores.
// ---------------------------------------------------------------------------
__global__ __launch_bounds__(256) void k_l1(
    const float* __restrict__ x, const unsigned short* __restrict__ bhi,
    const unsigned short* __restrict__ blo, _Float16* __restrict__ h1p) {
    int t = threadIdx.x;
    int l = t & 63;
    int wv = t >> 6;
    int rb = blockIdx.x & 255;
    int split = blockIdx.x >> 8;         // 0..5
    int gr0 = rb * 128 + wv * 32;
    int col = l & 31;
    int g2 = l >> 5;
    int gr = gr0 + col;
    const float* xrow = x + (size_t)(gr >> 4) * 8464 + (gr & 15);

    f32x16 acc0, acc1;
#pragma unroll
    for (int r = 0; r < 16; ++r) { acc0[r] = 0.f; acc1[r] = 0.f; }

    int i_lo = split * 89;
    int i_hi = i_lo + 89 < 529 ? i_lo + 89 : 529;

    float xv_nxt = xrow[(size_t)i_lo * 16];
#pragma unroll 1
    for (int i = i_lo; i < i_hi; ++i) {
        float xv = xv_nxt;
        int inx = i + 1;
        xv_nxt = (inx < i_hi) ? xrow[(size_t)inx * 16] : 0.f;

        float s0 = siluf(xv);
        float fm[8];
        bspline8(xv, fm);

        float av[8];
        av[0] = g2 ? fm[7] : s0;
#pragma unroll
        for (int j = 1; j < 8; ++j) av[j] = g2 ? 0.f : fm[j - 1];

        bf16x8 ahi, alo;
#pragma unroll
        for (int j = 0; j < 8; ++j) {
            union { float f; unsigned u; } a; a.f = av[j];
            unsigned short h = (unsigned short)(a.u >> 16);
            ahi[j] = (short)h;
            union { float f; unsigned u; } r; r.f = av[j] - bf2f(h);
            alo[j] = (short)(r.u >> 16);
        }

        const bf16x8* bh = (const bf16x8*)(bhi + ((size_t)i * 2) * 512 + (size_t)l * 8);
        const bf16x8* bl = (const bf16x8*)(blo + ((size_t)i * 2) * 512 + (size_t)l * 8);
        bf16x8 bh0 = bh[0], bh1 = bh[64];
        bf16x8 bl0 = bl[0], bl1 = bl[64];

        acc0 = __builtin_amdgcn_mfma_f32_32x32x16_bf16(ahi, bh0, acc0, 0, 0, 0);
        acc1 = __builtin_amdgcn_mfma_f32_32x32x16_bf16(ahi, bh1, acc1, 0, 0, 0);
        acc0 = __builtin_amdgcn_mfma_f32_32x32x16_bf16(ahi, bl0, acc0, 0, 0, 0);
        acc1 = __builtin_amdgcn_mfma_f32_32x32x16_bf16(ahi, bl1, acc1, 0, 0, 0);
        acc0 = __builtin_amdgcn_mfma_f32_32x32x16_bf16(alo, bh0, acc0, 0, 0, 0);
        acc1 = __builtin_amdgcn_mfma_f32_32x32x16_bf16(alo, bh1, acc1, 0, 0, 0);
    }

    _Float16* hp = h1p + (size_t)split * 1310720;
#pragma unroll
    for (int reg = 0; reg < 16; ++reg) {
        int rl = (reg & 3) + 8 * (reg >> 2) + 4 * g2;
        size_t g = (size_t)(gr0 + rl);
        hp[g * 40 + col] = (_Float16)acc0[reg];
        if (col < 8) hp[g * 40 + 32 + col] = (_Float16)acc1[reg];
    }
}

// ---------------------------------------------------------------------------
// k_l2: 512 blocks (128 rowchunks x 4 o-quarters) x 256 thr. Sum 6 f16
// partials through LDS (stride 41), thread = one row, 15 outputs.
// ---------------------------------------------------------------------------
__global__ __launch_bounds__(256) void k_l2(
    const _Float16* __restrict__ h1p, const float* __restrict__ w2t,
    float* __restrict__ h2d) {
    __shared__ float lds[256 * 41];
    int t = threadIdx.x;
    int rc = blockIdx.x >> 2;
    int oq = blockIdx.x & 3;
    size_t base = (size_t)rc * 10240;

#pragma unroll 1
    for (int e = t; e < 10240; e += 256) {
        int r = e / 40;
        int i = e - r * 40;
        float v = (float)h1p[base + e];
        v += (float)h1p[1310720 + base + e];
        v += (float)h1p[2621440 + base + e];
        v += (float)h1p[3932160 + base + e];
        v += (float)h1p[5242880 + base + e];
        v += (float)h1p[6553600 + base + e];
        lds[r * 41 + i] = v;
    }
    __syncthreads();

    float acc[15];
#pragma unroll
    for (int oo = 0; oo < 15; ++oo) acc[oo] = 0.f;

#pragma unroll 1
    for (int i = 0; i < 40; ++i) {
        float hv = lds[t * 41 + i];
        float f[9];
        f[0] = siluf(hv);
        bspline8(hv, f + 1);
        const float* wp = w2t + i * 540 + oq * 15;   // uniform -> s_load
#pragma unroll
        for (int q = 0; q < 9; ++q) {
            float fv = f[q];
#pragma unroll
            for (int oo = 0; oo < 15; ++oo)
                acc[oo] = fmaf(fv, wp[q * 60 + oo], acc[oo]);
        }
    }
    int gr = rc * 256 + t;
    int n = gr >> 4, w = gr & 15;
    float* op = h2d + (size_t)n * 960 + w;
#pragma unroll
    for (int oo = 0; oo < 15; ++oo)
        op[(size_t)(oq * 15 + oo) * 16] = acc[oo];
}

// ---------------------------------------------------------------------------
// k3: lin1 via MFMA. 256 blocks x 256 thr. Block b: row-tile rt = b>>2,
// col-quad cq = b&3; wave wv -> col-tile ct = cq*4+wv. Wave = 32 n x 32 u,
// K = 960 (60 steps). A (=h2d rows) split on the fly; B = whi/wlo.
// ---------------------------------------------------------------------------
__global__ __launch_bounds__(256) void k3(
    const float* __restrict__ h2d, const unsigned short* __restrict__ whi,
    const unsigned short* __restrict__ wlo, const float* __restrict__ lin1_b,
    float* __restrict__ h3) {
    int t = threadIdx.x;
    int l = t & 63;
    int wv = t >> 6;
    int rt = blockIdx.x >> 2;
    int ct = (blockIdx.x & 3) * 4 + wv;
    int col = l & 31;
    int g2 = l >> 5;
    int row = rt * 32 + col;
    const float* hrow = h2d + (size_t)row * 960 + g2 * 8;

    f32x16 acc;
#pragma unroll
    for (int r = 0; r < 16; ++r) acc[r] = 0.f;

#pragma unroll 1
    for (int dq = 0; dq < 60; ++dq) {
        float4 a0 = *(const float4*)(hrow + dq * 16);
        float4 a1 = *(const float4*)(hrow + dq * 16 + 4);
        float av[8] = {a0.x, a0.y, a0.z, a0.w, a1.x, a1.y, a1.z, a1.w};

        bf16x8 ahi, alo;
#pragma unroll
        for (int j = 0; j < 8; ++j) {
            union { float f; unsigned u; } a; a.f = av[j];
            unsigned short h = (unsigned short)(a.u >> 16);
            ahi[j] = (short)h;
            union { float f; unsigned u; } r; r.f = av[j] - bf2f(h);
            alo[j] = (short)(r.u >> 16);
        }

        size_t boff = ((size_t)(dq * 16 + ct) * 64 + l) * 8;
        bf16x8 bhv = *(const bf16x8*)(whi + boff);
        bf16x8 blv = *(const bf16x8*)(wlo + boff);

        acc = __builtin_amdgcn_mfma_f32_32x32x16_bf16(ahi, bhv, acc, 0, 0, 0);
        acc = __builtin_amdgcn_mfma_f32_32x32x16_bf16(ahi, blv, acc, 0, 0, 0);
        acc = __builtin_amdgcn_mfma_f32_32x32x16_bf16(alo, bhv, acc, 0, 0, 0);
    }

    int u = ct * 32 + col;
    float bu = lin1_b[u];
#pragma unroll
    for (int reg = 0; reg < 16; ++reg) {
        int rl = (reg & 3) + 8 * (reg >> 2) + 4 * g2;
        h3[(size_t)(rt * 32 + rl) * 512 + u] = acc[reg] + bu;
    }
}

// ---------------------------------------------------------------------------
// k4: head. 256 blocks x 512 thr, wave = one row n (8 rows/block).
// l2norm -> spline act -> lin2 -> l2norm -> f32 out.
// ---------------------------------------------------------------------------
__global__ __launch_bounds__(512) void k4(
    const float* __restrict__ h3, const float* __restrict__ act_base,
    const float* __restrict__ act_coeff, const float* __restrict__ lin2_w,
    const float* __restrict__ lin2_b, float* __restrict__ out) {
    int t = threadIdx.x;
    int wv = t >> 6, lane = t & 63;
    int n = blockIdx.x * 8 + wv;
    const float* hr = h3 + (size_t)n * 512;

    float xv[8];
#pragma unroll
    for (int k = 0; k < 8; ++k) xv[k] = hr[lane + 64 * k];
    float ss = 0.f;
#pragma unroll
    for (int k = 0; k < 8; ++k) ss = fmaf(xv[k], xv[k], ss);
#pragma unroll
    for (int d = 1; d < 64; d <<= 1) ss += __shfl_xor(ss, d, 64);
    float scale = 1.f / fmaxf(sqrtf(ss), 1e-12f);

    float act[8];
#pragma unroll
    for (int k = 0; k < 8; ++k) {
        int u = lane + 64 * k;
        float hn = xv[k] * scale;
        float s = siluf(hn);
        float fm[8];
        bspline8(hn, fm);
        float4 c0 = *(const float4*)(act_coeff + (size_t)u * 8);
        float4 c1 = *(const float4*)(act_coeff + (size_t)u * 8 + 4);
        float a = act_base[u] * s;
        a = fmaf(fm[0], c0.x, a);
        a = fmaf(fm[1], c0.y, a);
        a = fmaf(fm[2], c0.z, a);
        a = fmaf(fm[3], c0.w, a);
        a = fmaf(fm[4], c1.x, a);
        a = fmaf(fm[5], c1.y, a);
        a = fmaf(fm[6], c1.z, a);
        a = fmaf(fm[7], c1.w, a);
        act[k] = a;
    }

    float y = 0.f;
#pragma unroll
    for (int v = 0; v < 16; ++v) {
        float pv = 0.f;
#pragma unroll
        for (int k = 0; k < 8; ++k)
            pv = fmaf(act[k], lin2_w[v * 512 + lane + 64 * k], pv);
#pragma unroll
        for (int d = 1; d < 64; d <<= 1) pv += __shfl_xor(pv, d, 64);
        if (lane == v) y = pv + lin2_b[v];
    }
    float qq = y * y;                 // lanes >= 16 hold y = 0
#pragma unroll
    for (int d = 1; d < 16; d <<= 1) qq += __shfl_xor(qq, d, 64);
    float sc2 = 1.f / fmaxf(sqrtf(qq), 1e-12f);
    if (lane < 16)
        out[(size_t)n * 16 + lane] = y * sc2;
}

// ---------------------------------------------------------------------------
extern "C" void kernel_launch(void* const* d_in, const int* in_sizes, int n_in,
                              void* d_out, int out_size, void* d_ws,
                              size_t ws_size, hipStream_t stream) {
    auto find = [&](int sz, int occur) -> const float* {
        int seen = 0;
        for (int i = 0; i < n_in; ++i) {
            if (in_sizes[i] == sz) {
                if (seen == occur) return (const float*)d_in[i];
                ++seen;
            }
        }
        return nullptr;
    };
    const float* x         = find(17334272, 0);
    const float* base_w1   = find(21160, 0);
    const float* spline_w1 = find(169280, 0);
    const float* base_w2   = find(2400, 0);
    const float* spline_w2 = find(19200, 0);
    const float* lin1_w    = find(491520, 0);
    const float* lin1_b    = find(512, 0);
    const float* act_base  = find(512, 1);
    const float* act_coeff = find(4096, 0);
    const float* lin2_w    = find(8192, 0);
    const float* lin2_b    = find(16, 0);
    if (!x || !base_w1 || !spline_w1 || !base_w2 || !spline_w2 || !lin1_w ||
        !lin1_b || !act_base || !act_coeff || !lin2_w || !lin2_b) {
        x         = (const float*)d_in[0];
        base_w1   = (const float*)d_in[3];
        spline_w1 = (const float*)d_in[4];
        base_w2   = (const float*)d_in[6];
        spline_w2 = (const float*)d_in[7];
        lin1_w    = (const float*)d_in[8];
        lin1_b    = (const float*)d_in[9];
        act_base  = (const float*)d_in[11];
        act_coeff = (const float*)d_in[12];
        lin2_w    = (const float*)d_in[13];
        lin2_b    = (const float*)d_in[14];
    }

    char* ws = (char*)d_ws;
    float* w2t = (float*)ws;                              // 86,400 B
    unsigned short* whi = (unsigned short*)(ws + 86400);  // 983,040 B
    unsigned short* wlo = (unsigned short*)(ws + 1069440);// 983,040 B
    float* h2d = (float*)(ws + 2052480);                  // 7,864,320 B
    // bhi/blo alias h2d: written by k_prep, read by k_l1, overwritten by k_l2
    unsigned short* bhi = (unsigned short*)(ws + 2052480);
    unsigned short* blo = bhi + 541696;                   // 2 x 1,083,392 B
    _Float16* h1p = (_Float16*)(ws + 9916800);            // 6 x 2,621,440 B
    float* h3 = (float*)(ws + 25645440);                  // 4,194,304 B
    // total 29,839,744 B (< 30.67 MB proven in r0)

    k_prep<<<1024, 256, 0, stream>>>(base_w1, spline_w1, base_w2, spline_w2,
                                     lin1_w, bhi, blo, whi, wlo, w2t);
    k_l1<<<1536, 256, 0, stream>>>(x, bhi, blo, h1p);
    k_l2<<<512, 256, 0, stream>>>(h1p, w2t, h2d);
    k3<<<256, 256, 0, stream>>>(h2d, whi, wlo, lin1_b, h3);
    k4<<<256, 512, 0, stream>>>(h3, act_base, act_coeff, lin2_w, lin2_b,
                                (float*)d_out);
}

// Round 9
// 328.397 us; speedup vs baseline: 1.5074x; 1.1568x over previous
//
#include <hip/hip_runtime.h>

// ---------------------------------------------------------------------------
// KAN net. gr = n*16 + w; xa[gr,i] = x[n*8464 + i*16 + w].
// k_l1: layer1 (32768,529)->(32768,40) as TWO GEMMs on 32x32x16 bf16 MFMA:
//   spline: K = i*8+m (529*8=4232, 2 i/step, zero k-waste), A-pairs packed
//           directly via 5-candidate select on cell index c.
//   silu:   K = i (529, 16 i/step).
//   3-term hi/lo split precision. 6-way K-split -> h1p[6] f16 partials.
// k_l2: sum 6 f16 partials (vector loads, LDS as indexed scratch),
//       layer2 (40->60) f32 VALU -> h2d[n][o*16+w]
// k3:   lin1 via MFMA (validated r8).  k4: head (validated r5).
// ws 29.84 MB; spline/silu B arrays alias h2d region (dead before k_l2).
// ---------------------------------------------------------------------------

typedef short bf16x8 __attribute__((ext_vector_type(8)));
typedef unsigned u32x4 __attribute__((ext_vector_type(4)));
typedef float f32x16 __attribute__((ext_vector_type(16)));
typedef _Float16 f16x8 __attribute__((ext_vector_type(8)));

__device__ __forceinline__ float siluf(float x) { return x / (1.f + __expf(-x)); }

__device__ __forceinline__ unsigned short f2bf_rne(float v) {
    union { float f; unsigned u; } a; a.f = v;
    return (unsigned short)((a.u + 0x7fffu + ((a.u >> 16) & 1u)) >> 16);
}
__device__ __forceinline__ float bf2f(unsigned short h) {
    union { unsigned u; float f; } a; a.u = ((unsigned)h) << 16;
    return a.f;
}

// Dense 8-wide cubic B-spline, uniform grid t_j=(j-3)*0.4-1 (validated vs
// literal Cox-de Boor in the r2 bisection build).
__device__ __forceinline__ void bspline8(float x, float fm[8]) {
    float tpos = (x + 2.2f) * 2.5f;
    float fc = floorf(tpos);
    int c = (int)fc;
    float u = tpos - fc;
    bool valid = (c >= 0) && (c <= 10);
    float om = 1.f - u;
    float u2 = u * u, u3 = u2 * u;
    float W0 = om * om * om * (1.f / 6.f);
    float W1 = (3.f * u3 - 6.f * u2 + 4.f) * (1.f / 6.f);
    float W2 = (-3.f * u3 + 3.f * u2 + 3.f * u + 1.f) * (1.f / 6.f);
    float W3 = u3 * (1.f / 6.f);
#pragma unroll
    for (int m = 0; m < 8; ++m) {
        int d = c - m;
        float v = (d == 3) ? W0 : 0.f;
        v = (d == 2) ? W1 : v;
        v = (d == 1) ? W2 : v;
        v = (d == 0) ? W3 : v;
        fm[m] = valid ? v : 0.f;
    }
}

// ---------------------------------------------------------------------------
// k_prep:
//  bsh/bsl[((kk*2+nt)*64+l)*8+j]: spline B, k = kk*16+(l>>5)*8+j ->
//     i = 2*kk+(l>>5), m = j; o = nt*32+(l&31). 265 kk-steps.
//  bbh/bbl[((kk*2+nt)*64+l)*8+j]: silu B, i = kk*16+(l>>5)*8+j. 34 kk-steps.
//  whi/wlo[((dq*16+ct)*64+l)*8+j]: lin1_w[u=ct*32+(l&31)][k=dq*16+(l>>5)*8+j]
//  w2t[i][q][60]
// ---------------------------------------------------------------------------
__global__ __launch_bounds__(256) void k_prep(
    const float* __restrict__ base_w1, const float* __restrict__ spline_w1,
    const float* __restrict__ base_w2, const float* __restrict__ spline_w2,
    const float* __restrict__ lin1_w,
    unsigned short* __restrict__ bsh, unsigned short* __restrict__ bsl,
    unsigned short* __restrict__ bbh, unsigned short* __restrict__ bbl,
    unsigned short* __restrict__ whi, unsigned short* __restrict__ wlo,
    float* __restrict__ w2t) {
    int gid = blockIdx.x * 256 + threadIdx.x;
    int stride = gridDim.x * 256;
    for (int idx = gid; idx < 265 * 2 * 512; idx += stride) {
        int j = idx & 7;
        int l = (idx >> 3) & 63;
        int ntkk = idx >> 9;
        int nt = ntkk & 1;
        int kk = ntkk >> 1;
        int i = 2 * kk + (l >> 5);
        int o = nt * 32 + (l & 31);
        float val = 0.f;
        if (o < 40 && i < 529) val = spline_w1[(o * 529 + i) * 8 + j];
        unsigned short h = f2bf_rne(val);
        bsh[idx] = h;
        bsl[idx] = f2bf_rne(val - bf2f(h));
    }
    for (int idx = gid; idx < 34 * 2 * 512; idx += stride) {
        int j = idx & 7;
        int l = (idx >> 3) & 63;
        int ntkk = idx >> 9;
        int nt = ntkk & 1;
        int kk = ntkk >> 1;
        int i = kk * 16 + ((l >> 5) << 3) + j;
        int o = nt * 32 + (l & 31);
        float val = 0.f;
        if (o < 40 && i < 529) val = base_w1[o * 529 + i];
        unsigned short h = f2bf_rne(val);
        bbh[idx] = h;
        bbl[idx] = f2bf_rne(val - bf2f(h));
    }
    for (int idx = gid; idx < 60 * 16 * 512; idx += stride) {
        int j = idx & 7;
        int l = (idx >> 3) & 63;
        int ctdq = idx >> 9;
        int ct = ctdq & 15;
        int dq = ctdq >> 4;
        int k = dq * 16 + ((l >> 5) << 3) + j;
        int u = ct * 32 + (l & 31);
        float val = lin1_w[(size_t)u * 960 + k];
        unsigned short h = f2bf_rne(val);
        whi[idx] = h;
        wlo[idx] = f2bf_rne(val - bf2f(h));
    }
    for (int idx = gid; idx < 40 * 540; idx += stride) {
        int i = idx / 540;
        int rem = idx - i * 540;
        int q = rem / 60;
        int o = rem - q * 60;
        w2t[idx] = (q == 0) ? base_w2[o * 40 + i]
                            : spline_w2[(o * 40 + i) * 8 + (q - 1)];
    }
}

// ---------------------------------------------------------------------------
// k_l1: 1536 blocks (256 row-blocks x 6 K-splits) x 256 thr (4 waves).
// Wave = 32 rows. Lane: row/col = l&31, k-octet g2 = l>>5.
// ---------------------------------------------------------------------------
__global__ __launch_bounds__(256) void k_l1(
    const float* __restrict__ x,
    const unsigned short* __restrict__ bsh, const unsigned short* __restrict__ bsl,
    const unsigned short* __restrict__ bbh, const unsigned short* __restrict__ bbl,
    _Float16* __restrict__ h1p) {
    int t = threadIdx.x;
    int l = t & 63;
    int wv = t >> 6;
    int rb = blockIdx.x & 255;
    int split = blockIdx.x >> 8;         // 0..5
    int gr0 = rb * 128 + wv * 32;
    int col = l & 31;
    int g2 = l >> 5;
    int gr = gr0 + col;
    const float* xrow = x + (size_t)(gr >> 4) * 8464 + (gr & 15);
    const unsigned M = 0xFFFF0000u;

    f32x16 acc0, acc1;
#pragma unroll
    for (int r = 0; r < 16; ++r) { acc0[r] = 0.f; acc1[r] = 0.f; }

    // ---- silu GEMM: 16 i per step -------------------------------------
    int sk0 = split * 6;
    int sk1 = sk0 + 6; if (sk1 > 34) sk1 = 34;
#pragma unroll 1
    for (int kk = sk0; kk < sk1; ++kk) {
        int ib = kk * 16 + 8 * g2;
        unsigned hw[4], lw[4];
#pragma unroll
        for (int p = 0; p < 4; ++p) {
            int i0 = ib + 2 * p, i1 = i0 + 1;
            float x0 = (i0 < 529) ? xrow[(size_t)i0 * 16] : 0.f;
            float x1 = (i1 < 529) ? xrow[(size_t)i1 * 16] : 0.f;
            float s0 = siluf(x0), s1 = siluf(x1);
            unsigned u0 = __float_as_uint(s0), u1 = __float_as_uint(s1);
            hw[p] = (u0 >> 16) | (u1 & M);
            float r0 = s0 - __uint_as_float(u0 & M);
            float r1 = s1 - __uint_as_float(u1 & M);
            lw[p] = (__float_as_uint(r0) >> 16) | (__float_as_uint(r1) & M);
        }
        u32x4 hv = {hw[0], hw[1], hw[2], hw[3]};
        u32x4 lv = {lw[0], lw[1], lw[2], lw[3]};
        bf16x8 ah = __builtin_bit_cast(bf16x8, hv);
        bf16x8 al = __builtin_bit_cast(bf16x8, lv);

        size_t boff = ((size_t)kk * 2) * 512 + (size_t)l * 8;
        bf16x8 bh0 = *(const bf16x8*)(bbh + boff);
        bf16x8 bh1 = *(const bf16x8*)(bbh + boff + 512);
        bf16x8 bl0 = *(const bf16x8*)(bbl + boff);
        bf16x8 bl1 = *(const bf16x8*)(bbl + boff + 512);

        acc0 = __builtin_amdgcn_mfma_f32_32x32x16_bf16(ah, bh0, acc0, 0, 0, 0);
        acc1 = __builtin_amdgcn_mfma_f32_32x32x16_bf16(ah, bh1, acc1, 0, 0, 0);
        acc0 = __builtin_amdgcn_mfma_f32_32x32x16_bf16(ah, bl0, acc0, 0, 0, 0);
        acc1 = __builtin_amdgcn_mfma_f32_32x32x16_bf16(ah, bl1, acc1, 0, 0, 0);
        acc0 = __builtin_amdgcn_mfma_f32_32x32x16_bf16(al, bh0, acc0, 0, 0, 0);
        acc1 = __builtin_amdgcn_mfma_f32_32x32x16_bf16(al, bh1, acc1, 0, 0, 0);
    }

    // ---- spline GEMM: 2 i per step (k = i*8 + m) ----------------------
    int pk0 = split * 45;
    int pk1 = pk0 + 45; if (pk1 > 265) pk1 = 265;
#pragma unroll 1
    for (int kk = pk0; kk < pk1; ++kk) {
        int i0 = 2 * kk + g2;
        float xv = (i0 < 529) ? xrow[(size_t)i0 * 16] : 0.f;
        float tpos = (xv + 2.2f) * 2.5f;
        float fc = floorf(tpos);
        int c = (int)fc;
        float u = tpos - fc;
        bool valid = (c >= 0) && (c <= 10) && (i0 < 529);
        int cI = valid ? c : 1000;
        float om = 1.f - u;
        float u2 = u * u, u3 = u2 * u;
        float W0 = om * om * om * (1.f / 6.f);
        float W1 = (3.f * u3 - 6.f * u2 + 4.f) * (1.f / 6.f);
        float W2 = (-3.f * u3 + 3.f * u2 + 3.f * u + 1.f) * (1.f / 6.f);
        float W3 = u3 * (1.f / 6.f);

        unsigned ub0 = __float_as_uint(W0), ub1 = __float_as_uint(W1);
        unsigned ub2 = __float_as_uint(W2), ub3 = __float_as_uint(W3);
        float L0 = W0 - __uint_as_float(ub0 & M);
        float L1 = W1 - __uint_as_float(ub1 & M);
        float L2 = W2 - __uint_as_float(ub2 & M);
        float L3 = W3 - __uint_as_float(ub3 & M);
        unsigned ul0 = __float_as_uint(L0), ul1 = __float_as_uint(L1);
        unsigned ul2 = __float_as_uint(L2), ul3 = __float_as_uint(L3);

        // pair candidates by s = c - 2p: (fm[2p], fm[2p+1]) packed bf16
        unsigned PH[5], PL[5];
        PH[0] = ub3 >> 16;              PL[0] = ul3 >> 16;              // (W3,0)
        PH[1] = (ub2 >> 16) | (ub3 & M); PL[1] = (ul2 >> 16) | (ul3 & M);
        PH[2] = (ub1 >> 16) | (ub2 & M); PL[2] = (ul1 >> 16) | (ul2 & M);
        PH[3] = (ub0 >> 16) | (ub1 & M); PL[3] = (ul0 >> 16) | (ul1 & M);
        PH[4] = ub0 & M;                PL[4] = ul0 & M;                // (0,W0)

        unsigned hw[4], lw[4];
#pragma unroll
        for (int p = 0; p < 4; ++p) {
            int s = cI - 2 * p;
            unsigned h = 0, lo = 0;
            h = (s == 0) ? PH[0] : h;  lo = (s == 0) ? PL[0] : lo;
            h = (s == 1) ? PH[1] : h;  lo = (s == 1) ? PL[1] : lo;
            h = (s == 2) ? PH[2] : h;  lo = (s == 2) ? PL[2] : lo;
            h = (s == 3) ? PH[3] : h;  lo = (s == 3) ? PL[3] : lo;
            h = (s == 4) ? PH[4] : h;  lo = (s == 4) ? PL[4] : lo;
            hw[p] = h; lw[p] = lo;
        }
        u32x4 hv = {hw[0], hw[1], hw[2], hw[3]};
        u32x4 lv = {lw[0], lw[1], lw[2], lw[3]};
        bf16x8 ah = __builtin_bit_cast(bf16x8, hv);
        bf16x8 al = __builtin_bit_cast(bf16x8, lv);

        size_t boff = ((size_t)kk * 2) * 512 + (size_t)l * 8;
        bf16x8 bh0 = *(const bf16x8*)(bsh + boff);
        bf16x8 bh1 = *(const bf16x8*)(bsh + boff + 512);
        bf16x8 bl0 = *(const bf16x8*)(bsl + boff);
        bf16x8 bl1 = *(const bf16x8*)(bsl + boff + 512);

        acc0 = __builtin_amdgcn_mfma_f32_32x32x16_bf16(ah, bh0, acc0, 0, 0, 0);
        acc1 = __builtin_amdgcn_mfma_f32_32x32x16_bf16(ah, bh1, acc1, 0, 0, 0);
        acc0 = __builtin_amdgcn_mfma_f32_32x32x16_bf16(ah, bl0, acc0, 0, 0, 0);
        acc1 = __builtin_amdgcn_mfma_f32_32x32x16_bf16(ah, bl1, acc1, 0, 0, 0);
        acc0 = __builtin_amdgcn_mfma_f32_32x32x16_bf16(al, bh0, acc0, 0, 0, 0);
        acc1 = __builtin_amdgcn_mfma_f32_32x32x16_bf16(al, bh1, acc1, 0, 0, 0);
    }

    // D: col = l&31, row = (reg&3) + 8*(reg>>2) + 4*g2
    _Float16* hp = h1p + (size_t)split * 1310720;
#pragma unroll
    for (int reg = 0; reg < 16; ++reg) {
        int rl = (reg & 3) + 8 * (reg >> 2) + 4 * g2;
        size_t g = (size_t)(gr0 + rl);
        hp[g * 40 + col] = (_Float16)acc0[reg];
        if (col < 8) hp[g * 40 + 32 + col] = (_Float16)acc1[reg];
    }
}

// ---------------------------------------------------------------------------
// k_l2: 512 blocks (128 rowchunks x 4 o-quarters) x 256 thr. Thread = one
// row: vector-load + sum 6 f16 partials (30x16B loads, MLP), park row in LDS
// (stride 41, conflict-free) as indexed scratch, then 15 outputs.
// ---------------------------------------------------------------------------
__global__ __launch_bounds__(256) void k_l2(
    const _Float16* __restrict__ h1p, const float* __restrict__ w2t,
    float* __restrict__ h2d) {
    __shared__ float lds[256 * 41];
    int t = threadIdx.x;
    int rc = blockIdx.x >> 2;
    int oq = blockIdx.x & 3;
    int gr = rc * 256 + t;

    const f16x8* p0 = (const f16x8*)(h1p + (size_t)gr * 40);
#pragma unroll
    for (int cc = 0; cc < 5; ++cc) {
        f16x8 v = p0[cc];
        float s[8];
#pragma unroll
        for (int j = 0; j < 8; ++j) s[j] = (float)v[j];
#pragma unroll
        for (int sp = 1; sp < 6; ++sp) {
            f16x8 w = p0[(size_t)sp * 163840 + cc];
#pragma unroll
            for (int j = 0; j < 8; ++j) s[j] += (float)w[j];
        }
#pragma unroll
        for (int j = 0; j < 8; ++j) lds[t * 41 + cc * 8 + j] = s[j];
    }
    // no barrier: each thread reads only its own LDS row

    float acc[15];
#pragma unroll
    for (int oo = 0; oo < 15; ++oo) acc[oo] = 0.f;

#pragma unroll 1
    for (int i = 0; i < 40; ++i) {
        float hv = lds[t * 41 + i];
        float f[9];
        f[0] = siluf(hv);
        bspline8(hv, f + 1);
        const float* wp = w2t + i * 540 + oq * 15;   // uniform -> s_load
#pragma unroll
        for (int q = 0; q < 9; ++q) {
            float fv = f[q];
#pragma unroll
            for (int oo = 0; oo < 15; ++oo)
                acc[oo] = fmaf(fv, wp[q * 60 + oo], acc[oo]);
        }
    }
    int n = gr >> 4, w = gr & 15;
    float* op = h2d + (size_t)n * 960 + w;
#pragma unroll
    for (int oo = 0; oo < 15; ++oo)
        op[(size_t)(oq * 15 + oo) * 16] = acc[oo];
}

// ---------------------------------------------------------------------------
// k3: lin1 via MFMA (r8, validated). 256 blocks x 256 thr.
// ---------------------------------------------------------------------------
__global__ __launch_bounds__(256) void k3(
    const float* __restrict__ h2d, const unsigned short* __restrict__ whi,
    const unsigned short* __restrict__ wlo, const float* __restrict__ lin1_b,
    float* __restrict__ h3) {
    int t = threadIdx.x;
    int l = t & 63;
    int wv = t >> 6;
    int rt = blockIdx.x >> 2;
    int ct = (blockIdx.x & 3) * 4 + wv;
    int col = l & 31;
    int g2 = l >> 5;
    int row = rt * 32 + col;
    const float* hrow = h2d + (size_t)row * 960 + g2 * 8;
    const unsigned M = 0xFFFF0000u;

    f32x16 acc;
#pragma unroll
    for (int r = 0; r < 16; ++r) acc[r] = 0.f;

#pragma unroll 1
    for (int dq = 0; dq < 60; ++dq) {
        float4 a0 = *(const float4*)(hrow + dq * 16);
        float4 a1 = *(const float4*)(hrow + dq * 16 + 4);
        float av[8] = {a0.x, a0.y, a0.z, a0.w, a1.x, a1.y, a1.z, a1.w};

        unsigned hw[4], lw[4];
#pragma unroll
        for (int p = 0; p < 4; ++p) {
            unsigned u0 = __float_as_uint(av[2 * p]);
            unsigned u1 = __float_as_uint(av[2 * p + 1]);
            hw[p] = (u0 >> 16) | (u1 & M);
            float r0 = av[2 * p] - __uint_as_float(u0 & M);
            float r1 = av[2 * p + 1] - __uint_as_float(u1 & M);
            lw[p] = (__float_as_uint(r0) >> 16) | (__float_as_uint(r1) & M);
        }
        u32x4 hv = {hw[0], hw[1], hw[2], hw[3]};
        u32x4 lv = {lw[0], lw[1], lw[2], lw[3]};
        bf16x8 ahi = __builtin_bit_cast(bf16x8, hv);
        bf16x8 alo = __builtin_bit_cast(bf16x8, lv);

        size_t boff = ((size_t)(dq * 16 + ct) * 64 + l) * 8;
        bf16x8 bhv = *(const bf16x8*)(whi + boff);
        bf16x8 blv = *(const bf16x8*)(wlo + boff);

        acc = __builtin_amdgcn_mfma_f32_32x32x16_bf16(ahi, bhv, acc, 0, 0, 0);
        acc = __builtin_amdgcn_mfma_f32_32x32x16_bf16(ahi, blv, acc, 0, 0, 0);
        acc = __builtin_amdgcn_mfma_f32_32x32x16_bf16(alo, bhv, acc, 0, 0, 0);
    }

    int u = ct * 32 + col;
    float bu = lin1_b[u];
#pragma unroll
    for (int reg = 0; reg < 16; ++reg) {
        int rl = (reg & 3) + 8 * (reg >> 2) + 4 * g2;
        h3[(size_t)(rt * 32 + rl) * 512 + u] = acc[reg] + bu;
    }
}

// ---------------------------------------------------------------------------
// k4: head (r5, validated). 256 blocks x 512 thr, wave = one row n.
// ---------------------------------------------------------------------------
__global__ __launch_bounds__(512) void k4(
    const float* __restrict__ h3, const float* __restrict__ act_base,
    const float* __restrict__ act_coeff, const float* __restrict__ lin2_w,
    const float* __restrict__ lin2_b, float* __restrict__ out) {
    int t = threadIdx.x;
    int wv = t >> 6, lane = t & 63;
    int n = blockIdx.x * 8 + wv;
    const float* hr = h3 + (size_t)n * 512;

    float xv[8];
#pragma unroll
    for (int k = 0; k < 8; ++k) xv[k] = hr[lane + 64 * k];
    float ss = 0.f;
#pragma unroll
    for (int k = 0; k < 8; ++k) ss = fmaf(xv[k], xv[k], ss);
#pragma unroll
    for (int d = 1; d < 64; d <<= 1) ss += __shfl_xor(ss, d, 64);
    float scale = 1.f / fmaxf(sqrtf(ss), 1e-12f);

    float act[8];
#pragma unroll
    for (int k = 0; k < 8; ++k) {
        int u = lane + 64 * k;
        float hn = xv[k] * scale;
        float s = siluf(hn);
        float fm[8];
        bspline8(hn, fm);
        float4 c0 = *(const float4*)(act_coeff + (size_t)u * 8);
        float4 c1 = *(const float4*)(act_coeff + (size_t)u * 8 + 4);
        float a = act_base[u] * s;
        a = fmaf(fm[0], c0.x, a);
        a = fmaf(fm[1], c0.y, a);
        a = fmaf(fm[2], c0.z, a);
        a = fmaf(fm[3], c0.w, a);
        a = fmaf(fm[4], c1.x, a);
        a = fmaf(fm[5], c1.y, a);
        a = fmaf(fm[6], c1.z, a);
        a = fmaf(fm[7], c1.w, a);
        act[k] = a;
    }

    float y = 0.f;
#pragma unroll
    for (int v = 0; v < 16; ++v) {
        float pv = 0.f;
#pragma unroll
        for (int k = 0; k < 8; ++k)
            pv = fmaf(act[k], lin2_w[v * 512 + lane + 64 * k], pv);
#pragma unroll
        for (int d = 1; d < 64; d <<= 1) pv += __shfl_xor(pv, d, 64);
        if (lane == v) y = pv + lin2_b[v];
    }
    float qq = y * y;                 // lanes >= 16 hold y = 0
#pragma unroll
    for (int d = 1; d < 16; d <<= 1) qq += __shfl_xor(qq, d, 64);
    float sc2 = 1.f / fmaxf(sqrtf(qq), 1e-12f);
    if (lane < 16)
        out[(size_t)n * 16 + lane] = y * sc2;
}

// ---------------------------------------------------------------------------
extern "C" void kernel_launch(void* const* d_in, const int* in_sizes, int n_in,
                              void* d_out, int out_size, void* d_ws,
                              size_t ws_size, hipStream_t stream) {
    auto find = [&](int sz, int occur) -> const float* {
        int seen = 0;
        for (int i = 0; i < n_in; ++i) {
            if (in_sizes[i] == sz) {
                if (seen == occur) return (const float*)d_in[i];
                ++seen;
            }
        }
        return nullptr;
    };
    const float* x         = find(17334272, 0);
    const float* base_w1   = find(21160, 0);
    const float* spline_w1 = find(169280, 0);
    const float* base_w2   = find(2400, 0);
    const float* spline_w2 = find(19200, 0);
    const float* lin1_w    = find(491520, 0);
    const float* lin1_b    = find(512, 0);
    const float* act_base  = find(512, 1);
    const float* act_coeff = find(4096, 0);
    const float* lin2_w    = find(8192, 0);
    const float* lin2_b    = find(16, 0);
    if (!x || !base_w1 || !spline_w1 || !base_w2 || !spline_w2 || !lin1_w ||
        !lin1_b || !act_base || !act_coeff || !lin2_w || !lin2_b) {
        x         = (const float*)d_in[0];
        base_w1   = (const float*)d_in[3];
        spline_w1 = (const float*)d_in[4];
        base_w2   = (const float*)d_in[6];
        spline_w2 = (const float*)d_in[7];
        lin1_w    = (const float*)d_in[8];
        lin1_b    = (const float*)d_in[9];
        act_base  = (const float*)d_in[11];
        act_coeff = (const float*)d_in[12];
        lin2_w    = (const float*)d_in[13];
        lin2_b    = (const float*)d_in[14];
    }

    char* ws = (char*)d_ws;
    float* w2t = (float*)ws;                               //        86,400 B
    unsigned short* whi = (unsigned short*)(ws + 86400);   //       983,040 B
    unsigned short* wlo = (unsigned short*)(ws + 1069440); //       983,040 B
    float* h2d = (float*)(ws + 2052480);                   //     7,864,320 B
    // spline/silu B arrays alias h2d: prep writes, k_l1 reads, k_l2 overwrites
    unsigned short* bsh = (unsigned short*)(ws + 2052480); //       542,720 B
    unsigned short* bsl = (unsigned short*)(ws + 2595200); //       542,720 B
    unsigned short* bbh = (unsigned short*)(ws + 3137920); //        69,632 B
    unsigned short* bbl = (unsigned short*)(ws + 3207552); //        69,632 B
    _Float16* h1p = (_Float16*)(ws + 9916800);             // 6 x 2,621,440 B
    float* h3 = (float*)(ws + 25645440);                   //     4,194,304 B
    // total 29,839,744 B (< 30.67 MB proven usable in r0)

    k_prep<<<1024, 256, 0, stream>>>(base_w1, spline_w1, base_w2, spline_w2,
                                     lin1_w, bsh, bsl, bbh, bbl, whi, wlo, w2t);
    k_l1<<<1536, 256, 0, stream>>>(x, bsh, bsl, bbh, bbl, h1p);
    k_l2<<<512, 256, 0, stream>>>(h1p, w2t, h2d);
    k3<<<256, 256, 0, stream>>>(h2d, whi, wlo, lin1_b, h3);
    k4<<<256, 512, 0, stream>>>(h3, act_base, act_coeff, lin2_w, lin2_b,
                                (float*)d_out);
}